// Round 4
// baseline (251.810 us; speedup 1.0000x reference)
//
#include <hip/hip_runtime.h>

#define BATCH 256
#define QN 64
#define HN 2048
#define H2 (HN / 2)   // 1024
#define RPW 4         // rows per wave
#define WPB 4         // waves per block
#define RPB (RPW * WPB)  // 16 rows per block, all sharing one q

typedef float v4f __attribute__((ext_vector_type(4)));
typedef float v2f __attribute__((ext_vector_type(2)));

// Kernel A: factor[k][h] = prod_{j>k} W[k][j][h] * prod_{i<k} W[i][k][h]
// One thread per (k, h2) -> 65536 threads = 256 blocks. Coalesced in h.
__global__ __launch_bounds__(256) void factor_kernel(const float* __restrict__ W,
                                                     float* __restrict__ factor) {
    int idx = blockIdx.x * blockDim.x + threadIdx.x;
    int h2 = idx & (H2 - 1);
    int k  = idx >> 10;
    const v2f* W2 = (const v2f*)W;
    v2f p = {1.f, 1.f};
    #pragma unroll 8
    for (int j = k + 1; j < QN; ++j)
        p *= __builtin_nontemporal_load(&W2[(size_t)(k * QN + j) * H2 + h2]);
    #pragma unroll 8
    for (int i = 0; i < k; ++i)
        p *= __builtin_nontemporal_load(&W2[(size_t)(i * QN + k) * H2 + h2]);
    ((v2f*)factor)[(size_t)k * H2 + h2] = p;   // normal store -> stays in L2
}

// Kernel B: block = 4 waves, 16 rows, all with the SAME q. factor row staged
// once into LDS (barrier BEFORE x-loads so nothing big gets drained). Each
// wave owns 4 rows x 8 float4 = 32 HBM loads in flight; rows consumed in
// load order via compiler fine-grained vmcnt. 3 blocks/CU -> 384 loads/CU.
__global__ __launch_bounds__(256, 3) void normalize_kernel(const float* __restrict__ x,
                                                           const float* __restrict__ factor,
                                                           float* __restrict__ out) {
    __shared__ float fsh[HN];   // 8 KB
    const int t     = threadIdx.x;
    const int wave  = t >> 6;
    const int lane  = t & 63;
    const int q     = blockIdx.x >> 4;                         // 64 q's x 16 blocks
    const int bbase = (blockIdx.x & 15) * RPB + wave * RPW;    // batch index base

    // 1) stage factor[q] into LDS (2 loads/thread), barrier drains only these
    {
        const v4f* f4 = (const v4f*)(factor + (size_t)q * HN);
        v4f* s4 = (v4f*)fsh;
        s4[t]       = f4[t];
        s4[t + 256] = f4[t + 256];
    }
    __syncthreads();

    // 2) issue ALL x loads for this wave's 4 rows (32 nontemporal loads)
    v4f a[RPW][8];
    #pragma unroll
    for (int r = 0; r < RPW; ++r) {
        const v4f* x4 = (const v4f*)(x + ((size_t)(bbase + r) * QN + q) * HN);
        #pragma unroll
        for (int i = 0; i < 8; ++i)
            a[r][i] = __builtin_nontemporal_load(&x4[lane + 64 * i]);
    }

    // 3) consume rows in load order: multiply, reduce, scale, store
    const v4f* s4 = (const v4f*)fsh;
    #pragma unroll
    for (int r = 0; r < RPW; ++r) {
        float ss = 0.f;
        #pragma unroll
        for (int i = 0; i < 8; ++i) {
            v4f fi = s4[lane + 64 * i];
            a[r][i] *= fi;
            ss += a[r][i].x * a[r][i].x + a[r][i].y * a[r][i].y
                + a[r][i].z * a[r][i].z + a[r][i].w * a[r][i].w;
        }
        #pragma unroll
        for (int off = 32; off >= 1; off >>= 1)
            ss += __shfl_xor(ss, off, 64);
        float inv = 1.0f / fmaxf(sqrtf(ss), 1e-12f);

        v4f* o4 = (v4f*)(out + ((size_t)(bbase + r) * QN + q) * HN);
        #pragma unroll
        for (int i = 0; i < 8; ++i) {
            v4f yi = a[r][i] * inv;
            __builtin_nontemporal_store(yi, &o4[lane + 64 * i]);
        }
    }
}

extern "C" void kernel_launch(void* const* d_in, const int* in_sizes, int n_in,
                              void* d_out, int out_size, void* d_ws, size_t ws_size,
                              hipStream_t stream) {
    const float* x = (const float*)d_in[0];
    const float* W = (const float*)d_in[1];
    float* out     = (float*)d_out;
    float* factor  = (float*)d_ws;   // QN*HN floats = 512 KB

    factor_kernel<<<(QN * H2) / 256, 256, 0, stream>>>(W, factor);
    normalize_kernel<<<QN * (BATCH / RPB), 256, 0, stream>>>(x, factor, out);
}